// Round 1
// baseline (72.040 us; speedup 1.0000x reference)
//
#include <hip/hip_runtime.h>
#include <cmath>

#define BB 4
#define TT 8192
#define DD 1024
#define CL 128          // chunk length along T
#define NC 64           // TT / CL chunks

// y[b,t,d] = sum_{s<=t} x[b,s,d] * exp(-|decay_d|*(t-s)) * cos(freq_d*(t-s))
//          = Re(h[t]),  h[t] = r*h[t-1] + x[t],  r = exp(-|a|)*(cos w + i sin w)

// ---------- pass 1: per-chunk local scan, emit chunk-final complex state ----------
__global__ __launch_bounds__(256) void fftconv_pass1(
    const float* __restrict__ x, const float* __restrict__ decay,
    const float* __restrict__ freq, float2* __restrict__ carry)
{
    int g = blockIdx.x * 256 + threadIdx.x;      // B * NC * (D/2) threads
    int dp   = g & (DD / 2 - 1);                 // d-pair index
    int rest = g >> 9;
    int c = rest & (NC - 1);
    int b = rest >> 6;
    int d0 = dp << 1;

    float2 dc = *reinterpret_cast<const float2*>(decay + d0);
    float2 fq = *reinterpret_cast<const float2*>(freq + d0);
    float s, cc, e;
    e = expf(-fabsf(dc.x)); sincosf(fq.x, &s, &cc);
    float r0r = e * cc, r0i = e * s;
    e = expf(-fabsf(dc.y)); sincosf(fq.y, &s, &cc);
    float r1r = e * cc, r1i = e * s;

    const float* xp = x + (size_t)(b * TT + c * CL) * DD + d0;
    float h0r = 0.f, h0i = 0.f, h1r = 0.f, h1i = 0.f;
#pragma unroll 8
    for (int i = 0; i < CL; ++i) {
        float2 xv = *reinterpret_cast<const float2*>(xp);
        xp += DD;
        float t0 = fmaf(r0r, h0r, fmaf(-r0i, h0i, xv.x));
        h0i = fmaf(r0r, h0i, r0i * h0r);
        h0r = t0;
        float t1 = fmaf(r1r, h1r, fmaf(-r1i, h1i, xv.y));
        h1i = fmaf(r1r, h1i, r1i * h1r);
        h1r = t1;
    }
    *reinterpret_cast<float4*>(carry + (size_t)(b * NC + c) * DD + d0) =
        make_float4(h0r, h0i, h1r, h1i);
}

// ---------- pass 2: serial combine of chunk carries; slot <- exclusive incoming state ----------
__global__ __launch_bounds__(256) void fftconv_pass2(
    const float* __restrict__ decay, const float* __restrict__ freq,
    float2* __restrict__ carry)
{
    int g = blockIdx.x * 256 + threadIdx.x;      // B * (D/2) threads
    int dp = g & (DD / 2 - 1);
    int b  = g >> 9;
    int d0 = dp << 1;

    float2 dc = *reinterpret_cast<const float2*>(decay + d0);
    float2 fq = *reinterpret_cast<const float2*>(freq + d0);
    float s, cc, e;
    e = expf(-fabsf(dc.x) * (float)CL); sincosf(fq.x * (float)CL, &s, &cc);
    float R0r = e * cc, R0i = e * s;
    e = expf(-fabsf(dc.y) * (float)CL); sincosf(fq.y * (float)CL, &s, &cc);
    float R1r = e * cc, R1i = e * s;

    float s0r = 0.f, s0i = 0.f, s1r = 0.f, s1i = 0.f;
    for (int c = 0; c < NC; ++c) {
        float4* p = reinterpret_cast<float4*>(carry + (size_t)(b * NC + c) * DD + d0);
        float4 loc = *p;
        *p = make_float4(s0r, s0i, s1r, s1i);    // exclusive prefix (incoming state)
        float n0 = fmaf(R0r, s0r, fmaf(-R0i, s0i, loc.x));
        s0i = fmaf(R0r, s0i, fmaf(R0i, s0r, loc.y));
        s0r = n0;
        float n1 = fmaf(R1r, s1r, fmaf(-R1i, s1i, loc.z));
        s1i = fmaf(R1r, s1i, fmaf(R1i, s1r, loc.w));
        s1r = n1;
    }
}

// ---------- pass 3: rescan chunks seeded with incoming carry, write y = Re(h) ----------
__global__ __launch_bounds__(256) void fftconv_pass3(
    const float* __restrict__ x, const float* __restrict__ decay,
    const float* __restrict__ freq, const float2* __restrict__ carry,
    float* __restrict__ y)
{
    int g = blockIdx.x * 256 + threadIdx.x;      // B * NC * (D/2) threads
    int dp   = g & (DD / 2 - 1);
    int rest = g >> 9;
    int c = rest & (NC - 1);
    int b = rest >> 6;
    int d0 = dp << 1;

    float2 dc = *reinterpret_cast<const float2*>(decay + d0);
    float2 fq = *reinterpret_cast<const float2*>(freq + d0);
    float s, cc, e;
    e = expf(-fabsf(dc.x)); sincosf(fq.x, &s, &cc);
    float r0r = e * cc, r0i = e * s;
    e = expf(-fabsf(dc.y)); sincosf(fq.y, &s, &cc);
    float r1r = e * cc, r1i = e * s;

    float4 cin = *reinterpret_cast<const float4*>(carry + (size_t)(b * NC + c) * DD + d0);
    float h0r = cin.x, h0i = cin.y, h1r = cin.z, h1i = cin.w;

    size_t off = (size_t)(b * TT + c * CL) * DD + d0;
    const float* xp = x + off;
    float*       yp = y + off;
#pragma unroll 8
    for (int i = 0; i < CL; ++i) {
        float2 xv = *reinterpret_cast<const float2*>(xp);
        xp += DD;
        float t0 = fmaf(r0r, h0r, fmaf(-r0i, h0i, xv.x));
        h0i = fmaf(r0r, h0i, r0i * h0r);
        h0r = t0;
        float t1 = fmaf(r1r, h1r, fmaf(-r1i, h1i, xv.y));
        h1i = fmaf(r1r, h1i, r1i * h1r);
        h1r = t1;
        *reinterpret_cast<float2*>(yp) = make_float2(h0r, h1r);
        yp += DD;
    }
}

extern "C" void kernel_launch(void* const* d_in, const int* in_sizes, int n_in,
                              void* d_out, int out_size, void* d_ws, size_t ws_size,
                              hipStream_t stream) {
    const float* x     = (const float*)d_in[0];
    const float* decay = (const float*)d_in[1];
    const float* freq  = (const float*)d_in[2];
    float*       y     = (float*)d_out;
    float2*      carry = (float2*)d_ws;          // B*NC*D float2 = 2 MB

    const int thr13 = BB * NC * (DD / 2);        // 131072
    const int thr2  = BB * (DD / 2);             // 2048
    fftconv_pass1<<<thr13 / 256, 256, 0, stream>>>(x, decay, freq, carry);
    fftconv_pass2<<<thr2 / 256, 256, 0, stream>>>(decay, freq, carry);
    fftconv_pass3<<<thr13 / 256, 256, 0, stream>>>(x, decay, freq, carry, y);
}